// Round 6
// baseline (115.819 us; speedup 1.0000x reference)
//
#include <hip/hip_runtime.h>
#include <math.h>

#define B_SZ 8192
#define HID 256
#define DIM 128
#define MAXN 64
#define KM 160     // key_net mid
#define DM 192     // decoder mid
#define SM 128     // size_pred mid
#define LN_EPS 1e-5f

#define SP_BLOCKS 256          // sizepred blocks, 32 batches each
#define SP_BATCH 32
#define ZPAD 36                // z_s row stride (dwords)
#define FILL_BLOCKS 2048
#define DEC_BLOCKS 1024

// ---------------- Kernel 1: sizepred GEMM + row list (blocks 0..255) | keys (256..319) ----
__global__ void __launch_bounds__(256) sp_keys_kernel(
    const float* __restrict__ z,
    const float* __restrict__ kW1, const float* __restrict__ kb1,
    const float* __restrict__ kg,  const float* __restrict__ kbe,
    const float* __restrict__ kW2, const float* __restrict__ kb2,
    const float* __restrict__ sW1, const float* __restrict__ sb1,
    const float* __restrict__ sg,  const float* __restrict__ sbe,
    const float* __restrict__ sW2, const float* __restrict__ sb2,
    float* __restrict__ out_logits, float* __restrict__ out_nf,
    int* __restrict__ n_ws, int* __restrict__ cnt, int* __restrict__ list,
    float* __restrict__ keys)
{
    __shared__ float smem[HID * ZPAD];   // 36 KB
    const int blk = blockIdx.x;
    const int tid = threadIdx.x;

    if (blk >= SP_BLOCKS) {
        // ---------------- keys row j ----------------
        const int j = blk - SP_BLOCKS;
        float* red = smem;            // [256]
        float* t_s = smem + 256;      // [KM]

        float v = 0.f;
        if (tid < KM) v = kW1[j * KM + tid] + kb1[tid];

        red[tid] = (tid < KM) ? v : 0.f;
        __syncthreads();
        for (int s = 128; s > 0; s >>= 1) {
            if (tid < s) red[tid] += red[tid + s];
            __syncthreads();
        }
        const float mu = red[0] / (float)KM;
        __syncthreads();

        const float d = (tid < KM) ? (v - mu) : 0.f;
        red[tid] = d * d;
        __syncthreads();
        for (int s = 128; s > 0; s >>= 1) {
            if (tid < s) red[tid] += red[tid + s];
            __syncthreads();
        }
        const float rstd = rsqrtf(red[0] / (float)KM + LN_EPS);
        __syncthreads();

        if (tid < KM) t_s[tid] = tanhf(d * rstd * kg[tid] + kbe[tid]);
        __syncthreads();

        float acc = kb2[tid];
        #pragma unroll 4
        for (int k = 0; k < KM; ++k) acc = fmaf(t_s[k], kW2[k * HID + tid], acc);
        keys[j * HID + tid] = acc;
        return;
    }

    // ---------------- sizepred: 32 batches, H = Z @ sW1 then LN/ReLU/dot ----------------
    float (*z_s)[ZPAD] = (float(*)[ZPAD])smem;   // [256][36], z_s[k][b]
    const int b0 = blk * SP_BATCH;

    {
        const float4* z4 = (const float4*)z;
        #pragma unroll
        for (int i = 0; i < 8; ++i) {
            const int idx = tid + 256 * i;
            const int r = idx >> 6, c4 = idx & 63;
            const float4 v = z4[(size_t)(b0 + r) * 64 + c4];
            z_s[4 * c4 + 0][r] = v.x;
            z_s[4 * c4 + 1][r] = v.y;
            z_s[4 * c4 + 2][r] = v.z;
            z_s[4 * c4 + 3][r] = v.w;
        }
    }
    __syncthreads();

    const int cq = tid & 31;   // col quad: cols 4cq..4cq+3
    const int bg = tid >> 5;   // batch group: batches 4bg..4bg+3

    float acc[4][4];
    #pragma unroll
    for (int bi = 0; bi < 4; ++bi)
        #pragma unroll
        for (int ci = 0; ci < 4; ++ci) acc[bi][ci] = 0.f;

    const float4* w4p = (const float4*)sW1;
    #pragma unroll 4
    for (int k = 0; k < HID; ++k) {
        const float4 wv = w4p[k * 32 + cq];
        const float4 zb = *(const float4*)&z_s[k][bg * 4];
        const float zz[4] = {zb.x, zb.y, zb.z, zb.w};
        const float ww[4] = {wv.x, wv.y, wv.z, wv.w};
        #pragma unroll
        for (int bi = 0; bi < 4; ++bi)
            #pragma unroll
            for (int ci = 0; ci < 4; ++ci)
                acc[bi][ci] = fmaf(zz[bi], ww[ci], acc[bi][ci]);
    }

    const float4 g4v  = ((const float4*)sg)[cq];
    const float4 be4v = ((const float4*)sbe)[cq];
    const float4 w24v = ((const float4*)sW2)[cq];
    const float g4[4]  = {g4v.x, g4v.y, g4v.z, g4v.w};
    const float be4[4] = {be4v.x, be4v.y, be4v.z, be4v.w};
    const float w24[4] = {w24v.x, w24v.y, w24v.z, w24v.w};
    const float sb2v = sb2[0];
    const float b1_0 = sb1[4 * cq + 0], b1_1 = sb1[4 * cq + 1],
                b1_2 = sb1[4 * cq + 2], b1_3 = sb1[4 * cq + 3];

    #pragma unroll
    for (int bi = 0; bi < 4; ++bi) {
        float a[4] = {acc[bi][0] + b1_0, acc[bi][1] + b1_1,
                      acc[bi][2] + b1_2, acc[bi][3] + b1_3};
        float s = a[0] + a[1] + a[2] + a[3];
        #pragma unroll
        for (int off = 1; off < 32; off <<= 1) s += __shfl_xor(s, off, 64);
        const float mu = s * (1.f / (float)SM);
        float d[4], vs = 0.f;
        #pragma unroll
        for (int ci = 0; ci < 4; ++ci) { d[ci] = a[ci] - mu; vs = fmaf(d[ci], d[ci], vs); }
        #pragma unroll
        for (int off = 1; off < 32; off <<= 1) vs += __shfl_xor(vs, off, 64);
        const float rstd = rsqrtf(vs * (1.f / (float)SM) + LN_EPS);

        float p = 0.f;
        #pragma unroll
        for (int ci = 0; ci < 4; ++ci) {
            float h = fmaf(d[ci] * rstd, g4[ci], be4[ci]);
            h = fmaxf(h, 0.f);
            p = fmaf(h, w24[ci], p);
        }
        #pragma unroll
        for (int off = 1; off < 32; off <<= 1) p += __shfl_xor(p, off, 64);

        if (cq == 0) {
            const int b = b0 + bg * 4 + bi;
            const float logit = p + sb2v;
            int n = (int)rintf(logit);       // round-half-even == jnp.round
            n = min(max(n, 0), MAXN - 1);
            out_logits[b] = logit;
            out_nf[b] = (float)n;
            n_ws[b] = n;
            if (n > 0) {
                const int pos = atomicAdd(cnt, n);
                for (int jj = 0; jj < n; ++jj) list[pos + jj] = (b << 6) | jj;
            }
        }
    }
}

// ---------------- Kernel 2: lean fill of invalid rows only (no LDS, minimal VGPR) ----------
__global__ void __launch_bounds__(256) fill_kernel(
    const int* __restrict__ n_ws, float* __restrict__ out0)
{
    const int b0 = blockIdx.x * 4;
    const int tid = threadIdx.x;
    const float4 zf = make_float4(0.f, 0.f, 0.f, 0.f);
    #pragma unroll
    for (int bi = 0; bi < 4; ++bi) {
        const int n = n_ws[b0 + bi];                       // wave-uniform scalar load
        float4* o4 = (float4*)(out0 + (size_t)(b0 + bi) * (MAXN * DIM)) + n * 32;
        const int cnt4 = (MAXN - n) * 32;                  // <= 2048 float4
        for (int idx = tid; idx < cnt4; idx += 256) o4[idx] = zf;
    }
}

// ---------------- Kernel 3: decode valid rows, 4 rows per block-iteration ----------------
__global__ void __launch_bounds__(256) decode_kernel(
    const float* __restrict__ z, const float* __restrict__ keys,
    const int* __restrict__ cnt_ptr, const int* __restrict__ list,
    const float* __restrict__ dW1, const float* __restrict__ db1,
    const float* __restrict__ dW2, const float* __restrict__ db2,
    float* __restrict__ out0)
{
    __shared__ float s_s[HID][4];      // zp rows, k-major  (4 KB)
    __shared__ float t_s[DM][4];       // tanh(h)           (3 KB)
    __shared__ float hp[4][DM][4];     // GEMV1 partials    (12 KB)
    __shared__ float op[4][DIM][4];    // GEMV2 partials    (8 KB)

    const int cnt = *cnt_ptr;
    const int tid = threadIdx.x;
    const int w = tid >> 6, lane = tid & 63;

    for (int base = blockIdx.x * 4; base < cnt; base += DEC_BLOCKS * 4) {
        const int rcnt = min(4, cnt - base);
        int bs[4], js[4];
        #pragma unroll
        for (int r = 0; r < 4; ++r) {
            const int e = list[base + min(r, rcnt - 1)];
            bs[r] = e >> 6; js[r] = e & 63;
        }

        // stage s[k][r] = z[b_r][k] * keys[j_r][k]   (k == tid)
        #pragma unroll
        for (int r = 0; r < 4; ++r)
            s_s[tid][r] = z[(size_t)bs[r] * HID + tid] * keys[js[r] * HID + tid];
        __syncthreads();

        // GEMV1: wave w covers k in [64w, 64w+64); lane<48 owns cols 4lane..4lane+3
        if (lane < 48) {
            float a[4][4];
            #pragma unroll
            for (int r = 0; r < 4; ++r)
                #pragma unroll
                for (int c = 0; c < 4; ++c) a[r][c] = 0.f;
            const int k0 = w * 64;
            #pragma unroll 8
            for (int kk = 0; kk < 64; ++kk) {
                const int k = k0 + kk;
                const float4 wv = ((const float4*)dW1)[(size_t)k * 48 + lane];
                const float4 sv = *(const float4*)&s_s[k][0];
                const float sr[4] = {sv.x, sv.y, sv.z, sv.w};
                const float wc[4] = {wv.x, wv.y, wv.z, wv.w};
                #pragma unroll
                for (int r = 0; r < 4; ++r)
                    #pragma unroll
                    for (int c = 0; c < 4; ++c)
                        a[r][c] = fmaf(sr[r], wc[c], a[r][c]);
            }
            #pragma unroll
            for (int c = 0; c < 4; ++c)
                *(float4*)&hp[w][4 * lane + c][0] =
                    make_float4(a[0][c], a[1][c], a[2][c], a[3][c]);
        }
        __syncthreads();

        if (tid < DM) {
            const float4 p0 = *(const float4*)&hp[0][tid][0];
            const float4 p1 = *(const float4*)&hp[1][tid][0];
            const float4 p2 = *(const float4*)&hp[2][tid][0];
            const float4 p3 = *(const float4*)&hp[3][tid][0];
            const float bb = db1[tid];
            *(float4*)&t_s[tid][0] = make_float4(
                tanhf(p0.x + p1.x + p2.x + p3.x + bb),
                tanhf(p0.y + p1.y + p2.y + p3.y + bb),
                tanhf(p0.z + p1.z + p2.z + p3.z + bb),
                tanhf(p0.w + p1.w + p2.w + p3.w + bb));
        }
        __syncthreads();

        // GEMV2: wave w covers k in [48w, 48w+48); lane<32 owns cols 4lane..4lane+3
        if (lane < 32) {
            float o[4][4];
            #pragma unroll
            for (int r = 0; r < 4; ++r)
                #pragma unroll
                for (int c = 0; c < 4; ++c) o[r][c] = 0.f;
            const int k1 = w * 48;
            #pragma unroll 8
            for (int kk = 0; kk < 48; ++kk) {
                const int k = k1 + kk;
                const float4 wv = ((const float4*)dW2)[(size_t)k * 32 + lane];
                const float4 tv = *(const float4*)&t_s[k][0];
                const float tr[4] = {tv.x, tv.y, tv.z, tv.w};
                const float wc[4] = {wv.x, wv.y, wv.z, wv.w};
                #pragma unroll
                for (int r = 0; r < 4; ++r)
                    #pragma unroll
                    for (int c = 0; c < 4; ++c)
                        o[r][c] = fmaf(tr[r], wc[c], o[r][c]);
            }
            #pragma unroll
            for (int c = 0; c < 4; ++c)
                *(float4*)&op[w][4 * lane + c][0] =
                    make_float4(o[0][c], o[1][c], o[2][c], o[3][c]);
        }
        __syncthreads();

        if (tid < DIM) {
            const float4 q0 = *(const float4*)&op[0][tid][0];
            const float4 q1 = *(const float4*)&op[1][tid][0];
            const float4 q2 = *(const float4*)&op[2][tid][0];
            const float4 q3 = *(const float4*)&op[3][tid][0];
            const float bb = db2[tid];
            const float ov[4] = {q0.x + q1.x + q2.x + q3.x + bb,
                                 q0.y + q1.y + q2.y + q3.y + bb,
                                 q0.z + q1.z + q2.z + q3.z + bb,
                                 q0.w + q1.w + q2.w + q3.w + bb};
            #pragma unroll
            for (int r = 0; r < 4; ++r)
                if (r < rcnt)
                    out0[((size_t)bs[r] * MAXN + js[r]) * DIM + tid] = ov[r];
        }
        __syncthreads();
    }
}

extern "C" void kernel_launch(void* const* d_in, const int* in_sizes, int n_in,
                              void* d_out, int out_size, void* d_ws, size_t ws_size,
                              hipStream_t stream)
{
    const float* z   = (const float*)d_in[0];
    const float* kW1 = (const float*)d_in[1];
    const float* kb1 = (const float*)d_in[2];
    const float* kg  = (const float*)d_in[3];
    const float* kbe = (const float*)d_in[4];
    const float* kW2 = (const float*)d_in[5];
    const float* kb2 = (const float*)d_in[6];
    const float* dW1 = (const float*)d_in[7];
    const float* db1 = (const float*)d_in[8];
    const float* dW2 = (const float*)d_in[9];
    const float* db2 = (const float*)d_in[10];
    const float* sW1 = (const float*)d_in[11];
    const float* sb1 = (const float*)d_in[12];
    const float* sg  = (const float*)d_in[13];
    const float* sbe = (const float*)d_in[14];
    const float* sW2 = (const float*)d_in[15];
    const float* sb2 = (const float*)d_in[16];

    float* out0       = (float*)d_out;                         // [B, 64, 128]
    float* out_logits = out0 + (size_t)B_SZ * MAXN * DIM;      // [B, 1]
    float* out_nf     = out_logits + B_SZ;                     // [B]

    float* keys = (float*)d_ws;                                // 64 KB
    int*   cnt  = (int*)((char*)d_ws + 65536);                 // 4 B (+pad)
    int*   n_ws = (int*)((char*)d_ws + 65536 + 128);           // 32 KB
    int*   list = (int*)((char*)d_ws + 65536 + 128 + 32768);   // <= 2 MB

    hipMemsetAsync(cnt, 0, sizeof(int), stream);

    sp_keys_kernel<<<SP_BLOCKS + MAXN, 256, 0, stream>>>(
        z, kW1, kb1, kg, kbe, kW2, kb2,
        sW1, sb1, sg, sbe, sW2, sb2,
        out_logits, out_nf, n_ws, cnt, list, keys);

    fill_kernel<<<FILL_BLOCKS, 256, 0, stream>>>(n_ws, out0);

    decode_kernel<<<DEC_BLOCKS, 256, 0, stream>>>(
        z, keys, cnt, list, dW1, db1, dW2, db2, out0);
}

// Round 7
// 105.006 us; speedup vs baseline: 1.1030x; 1.1030x over previous
//
#include <hip/hip_runtime.h>
#include <math.h>

#define B_SZ 8192
#define HID 256
#define DIM 128
#define MAXN 64
#define KM 160     // key_net mid
#define DM 192     // decoder mid
#define SM 128     // size_pred mid
#define LN_EPS 1e-5f

// ---------------- Kernel 1: keys[64][256] = tanh(LN(kW1 + kb1)) @ kW2 + kb2 ----------------
__global__ void __launch_bounds__(256) keys_kernel(
    const float* __restrict__ kW1, const float* __restrict__ kb1,
    const float* __restrict__ kg,  const float* __restrict__ kbe,
    const float* __restrict__ kW2, const float* __restrict__ kb2,
    float* __restrict__ keys)
{
    __shared__ float red[256];
    __shared__ float t_s[KM];
    const int j = blockIdx.x;
    const int tid = threadIdx.x;

    float v = 0.f;
    if (tid < KM) v = kW1[j * KM + tid] + kb1[tid];

    red[tid] = (tid < KM) ? v : 0.f;
    __syncthreads();
    for (int s = 128; s > 0; s >>= 1) {
        if (tid < s) red[tid] += red[tid + s];
        __syncthreads();
    }
    const float mu = red[0] / (float)KM;
    __syncthreads();

    const float d = (tid < KM) ? (v - mu) : 0.f;
    red[tid] = d * d;
    __syncthreads();
    for (int s = 128; s > 0; s >>= 1) {
        if (tid < s) red[tid] += red[tid + s];
        __syncthreads();
    }
    const float rstd = rsqrtf(red[0] / (float)KM + LN_EPS);

    if (tid < KM) t_s[tid] = tanhf(d * rstd * kg[tid] + kbe[tid]);
    __syncthreads();

    float acc = kb2[tid];
    #pragma unroll 4
    for (int k = 0; k < KM; ++k) acc = fmaf(t_s[k], kW2[k * HID + tid], acc);
    keys[j * HID + tid] = acc;
}

// ---------------- Kernel 2: mega — sizepred + fill(j>=n) + decode(j<n), 4 batches/block ----
__global__ void __launch_bounds__(256) mega_kernel(
    const float* __restrict__ z, const float* __restrict__ keys,
    const float* __restrict__ sW1, const float* __restrict__ sb1,
    const float* __restrict__ sg,  const float* __restrict__ sbe,
    const float* __restrict__ sW2, const float* __restrict__ sb2,
    const float* __restrict__ dW1, const float* __restrict__ db1,
    const float* __restrict__ dW2, const float* __restrict__ db2,
    float* __restrict__ out0, float* __restrict__ out_logits,
    float* __restrict__ out_nf)
{
    __shared__ __align__(16) float z_s[4][HID];        // 4 KB
    __shared__ __align__(16) float s_s[HID][4];        // 4 KB
    __shared__ __align__(16) float t_s[DM][4];         // 3 KB
    __shared__ __align__(16) float pbuf[4 * DM * 4];   // 12 KB: hp, then reused as op
    __shared__ int n_s[4];
    __shared__ int rlist[4 * (MAXN - 1)];              // ~1 KB

    const int blk = blockIdx.x;
    const int tid = threadIdx.x;
    const int w = tid >> 6, lane = tid & 63;
    const int b0 = blk * 4;
    const int b = b0 + w;

    // stage this wave's z row (64 float4)
    ((float4*)z_s[w])[lane] = ((const float4*)(z + (size_t)b * HID))[lane];

    // ---- sizepred (wave-local; same-wave LDS readback, no barrier needed) ----
    {
        float a0 = sb1[lane], a1 = sb1[64 + lane];
        #pragma unroll 4
        for (int k = 0; k < HID; ++k) {
            const float s = z_s[w][k];
            a0 = fmaf(s, sW1[k * SM + lane], a0);
            a1 = fmaf(s, sW1[k * SM + 64 + lane], a1);
        }
        float sum = a0 + a1;
        #pragma unroll
        for (int off = 1; off < 64; off <<= 1) sum += __shfl_xor(sum, off, 64);
        const float mu = sum * (1.f / (float)SM);
        const float d0 = a0 - mu, d1 = a1 - mu;
        float vs = d0 * d0 + d1 * d1;
        #pragma unroll
        for (int off = 1; off < 64; off <<= 1) vs += __shfl_xor(vs, off, 64);
        const float rstd = rsqrtf(vs * (1.f / (float)SM) + LN_EPS);

        float h0 = d0 * rstd * sg[lane]      + sbe[lane];
        float h1 = d1 * rstd * sg[64 + lane] + sbe[64 + lane];
        h0 = fmaxf(h0, 0.f);
        h1 = fmaxf(h1, 0.f);

        float p = fmaf(h0, sW2[lane], h1 * sW2[64 + lane]);
        #pragma unroll
        for (int off = 1; off < 64; off <<= 1) p += __shfl_xor(p, off, 64);

        if (lane == 0) {
            const float logit = p + sb2[0];
            int n = (int)rintf(logit);       // round-half-even == jnp.round
            n = min(max(n, 0), MAXN - 1);
            out_logits[b] = logit;
            out_nf[b] = (float)n;
            n_s[w] = n;
        }
    }
    __syncthreads();

    // ---- fill invalid rows j >= n (disjoint from decoded rows) ----
    const float4 zf = make_float4(0.f, 0.f, 0.f, 0.f);
    #pragma unroll
    for (int bi = 0; bi < 4; ++bi) {
        const int n = n_s[bi];
        float4* o4 = (float4*)(out0 + (size_t)(b0 + bi) * (MAXN * DIM)) + n * 32;
        const int cnt4 = (MAXN - n) * 32;
        for (int idx = tid; idx < cnt4; idx += 256) o4[idx] = zf;
    }

    const int total = n_s[0] + n_s[1] + n_s[2] + n_s[3];
    if (total == 0) return;

    // ---- build block-local row list ----
    if (tid < 4) {
        int off = 0;
        for (int i = 0; i < tid; ++i) off += n_s[i];
        for (int j = 0; j < n_s[tid]; ++j) rlist[off + j] = (tid << 6) | j;
    }
    __syncthreads();

    float (*hp)[DM][4]  = (float(*)[DM][4])pbuf;    // GEMV1 partials
    float (*op)[DIM][4] = (float(*)[DIM][4])pbuf;   // GEMV2 partials (reuse after barrier)

    // ---- decode valid rows, 4 per iteration (R4-verified tile) ----
    for (int base = 0; base < total; base += 4) {
        const int rcnt = min(4, total - base);
        int bs[4], js[4];
        #pragma unroll
        for (int r = 0; r < 4; ++r) {
            const int e = rlist[base + min(r, rcnt - 1)];
            bs[r] = e >> 6; js[r] = e & 63;
        }

        // stage s[k][r] = z[b_r][k] * keys[j_r][k]   (k == tid; z from LDS)
        #pragma unroll
        for (int r = 0; r < 4; ++r)
            s_s[tid][r] = z_s[bs[r]][tid] * keys[js[r] * HID + tid];
        __syncthreads();

        // GEMV1: wave w covers k in [64w, 64w+64); lane<48 owns cols 4lane..4lane+3
        if (lane < 48) {
            float a[4][4];
            #pragma unroll
            for (int r = 0; r < 4; ++r)
                #pragma unroll
                for (int c = 0; c < 4; ++c) a[r][c] = 0.f;
            const int k0 = w * 64;
            #pragma unroll 8
            for (int kk = 0; kk < 64; ++kk) {
                const int k = k0 + kk;
                const float4 wv = ((const float4*)dW1)[(size_t)k * 48 + lane];
                const float4 sv = *(const float4*)&s_s[k][0];
                const float sr[4] = {sv.x, sv.y, sv.z, sv.w};
                const float wc[4] = {wv.x, wv.y, wv.z, wv.w};
                #pragma unroll
                for (int r = 0; r < 4; ++r)
                    #pragma unroll
                    for (int c = 0; c < 4; ++c)
                        a[r][c] = fmaf(sr[r], wc[c], a[r][c]);
            }
            #pragma unroll
            for (int c = 0; c < 4; ++c)
                *(float4*)&hp[w][4 * lane + c][0] =
                    make_float4(a[0][c], a[1][c], a[2][c], a[3][c]);
        }
        __syncthreads();

        if (tid < DM) {
            const float4 p0 = *(const float4*)&hp[0][tid][0];
            const float4 p1 = *(const float4*)&hp[1][tid][0];
            const float4 p2 = *(const float4*)&hp[2][tid][0];
            const float4 p3 = *(const float4*)&hp[3][tid][0];
            const float bb = db1[tid];
            *(float4*)&t_s[tid][0] = make_float4(
                tanhf(p0.x + p1.x + p2.x + p3.x + bb),
                tanhf(p0.y + p1.y + p2.y + p3.y + bb),
                tanhf(p0.z + p1.z + p2.z + p3.z + bb),
                tanhf(p0.w + p1.w + p2.w + p3.w + bb));
        }
        __syncthreads();   // also: hp reads done, safe to overwrite as op

        // GEMV2: wave w covers k in [48w, 48w+48); lane<32 owns cols 4lane..4lane+3
        if (lane < 32) {
            float o[4][4];
            #pragma unroll
            for (int r = 0; r < 4; ++r)
                #pragma unroll
                for (int c = 0; c < 4; ++c) o[r][c] = 0.f;
            const int k1 = w * 48;
            #pragma unroll 8
            for (int kk = 0; kk < 48; ++kk) {
                const int k = k1 + kk;
                const float4 wv = ((const float4*)dW2)[(size_t)k * 32 + lane];
                const float4 tv = *(const float4*)&t_s[k][0];
                const float tr[4] = {tv.x, tv.y, tv.z, tv.w};
                const float wc[4] = {wv.x, wv.y, wv.z, wv.w};
                #pragma unroll
                for (int r = 0; r < 4; ++r)
                    #pragma unroll
                    for (int c = 0; c < 4; ++c)
                        o[r][c] = fmaf(tr[r], wc[c], o[r][c]);
            }
            #pragma unroll
            for (int c = 0; c < 4; ++c)
                *(float4*)&op[w][4 * lane + c][0] =
                    make_float4(o[0][c], o[1][c], o[2][c], o[3][c]);
        }
        __syncthreads();

        if (tid < DIM) {
            const float4 q0 = *(const float4*)&op[0][tid][0];
            const float4 q1 = *(const float4*)&op[1][tid][0];
            const float4 q2 = *(const float4*)&op[2][tid][0];
            const float4 q3 = *(const float4*)&op[3][tid][0];
            const float bb = db2[tid];
            const float ov[4] = {q0.x + q1.x + q2.x + q3.x + bb,
                                 q0.y + q1.y + q2.y + q3.y + bb,
                                 q0.z + q1.z + q2.z + q3.z + bb,
                                 q0.w + q1.w + q2.w + q3.w + bb};
            #pragma unroll
            for (int r = 0; r < 4; ++r)
                if (r < rcnt)
                    out0[((size_t)(b0 + bs[r]) * MAXN + js[r]) * DIM + tid] = ov[r];
        }
        __syncthreads();   // protect s_s/t_s/op before next group
    }
}

extern "C" void kernel_launch(void* const* d_in, const int* in_sizes, int n_in,
                              void* d_out, int out_size, void* d_ws, size_t ws_size,
                              hipStream_t stream)
{
    const float* z   = (const float*)d_in[0];
    const float* kW1 = (const float*)d_in[1];
    const float* kb1 = (const float*)d_in[2];
    const float* kg  = (const float*)d_in[3];
    const float* kbe = (const float*)d_in[4];
    const float* kW2 = (const float*)d_in[5];
    const float* kb2 = (const float*)d_in[6];
    const float* dW1 = (const float*)d_in[7];
    const float* db1 = (const float*)d_in[8];
    const float* dW2 = (const float*)d_in[9];
    const float* db2 = (const float*)d_in[10];
    const float* sW1 = (const float*)d_in[11];
    const float* sb1 = (const float*)d_in[12];
    const float* sg  = (const float*)d_in[13];
    const float* sbe = (const float*)d_in[14];
    const float* sW2 = (const float*)d_in[15];
    const float* sb2 = (const float*)d_in[16];

    float* out0       = (float*)d_out;                         // [B, 64, 128]
    float* out_logits = out0 + (size_t)B_SZ * MAXN * DIM;      // [B, 1]
    float* out_nf     = out_logits + B_SZ;                     // [B]

    float* keys = (float*)d_ws;                                // 64 KB

    keys_kernel<<<MAXN, 256, 0, stream>>>(kW1, kb1, kg, kbe, kW2, kb2, keys);

    mega_kernel<<<B_SZ / 4, 256, 0, stream>>>(
        z, keys,
        sW1, sb1, sg, sbe, sW2, sb2,
        dW1, db1, dW2, db2,
        out0, out_logits, out_nf);
}

// Round 8
// 83.763 us; speedup vs baseline: 1.3827x; 1.2536x over previous
//
#include <hip/hip_runtime.h>
#include <math.h>

#define B_SZ 8192
#define HID 256
#define DIM 128
#define MAXN 64
#define KM 160     // key_net mid
#define DM 192     // decoder mid
#define SM 128     // size_pred mid
#define LN_EPS 1e-5f

#define SP_BLOCKS 256          // sizepred blocks, 32 batches each
#define SP_BATCH 32
#define ZPAD 36                // z_s row stride (dwords)

// ---------------- Kernel 1: sizepred GEMM (blocks 0..255) + keys (256..319) ----------------
__global__ void __launch_bounds__(256) sp_keys_kernel(
    const float* __restrict__ z,
    const float* __restrict__ kW1, const float* __restrict__ kb1,
    const float* __restrict__ kg,  const float* __restrict__ kbe,
    const float* __restrict__ kW2, const float* __restrict__ kb2,
    const float* __restrict__ sW1, const float* __restrict__ sb1,
    const float* __restrict__ sg,  const float* __restrict__ sbe,
    const float* __restrict__ sW2, const float* __restrict__ sb2,
    float* __restrict__ out_logits, float* __restrict__ out_nf,
    int* __restrict__ n_ws, float* __restrict__ keys)
{
    __shared__ float smem[HID * ZPAD];   // 36 KB
    const int blk = blockIdx.x;
    const int tid = threadIdx.x;

    if (blk >= SP_BLOCKS) {
        // ---------------- keys row j ----------------
        const int j = blk - SP_BLOCKS;
        float* red = smem;            // [256]
        float* t_s = smem + 256;      // [KM]

        float v = 0.f;
        if (tid < KM) v = kW1[j * KM + tid] + kb1[tid];

        red[tid] = (tid < KM) ? v : 0.f;
        __syncthreads();
        for (int s = 128; s > 0; s >>= 1) {
            if (tid < s) red[tid] += red[tid + s];
            __syncthreads();
        }
        const float mu = red[0] / (float)KM;
        __syncthreads();

        const float d = (tid < KM) ? (v - mu) : 0.f;
        red[tid] = d * d;
        __syncthreads();
        for (int s = 128; s > 0; s >>= 1) {
            if (tid < s) red[tid] += red[tid + s];
            __syncthreads();
        }
        const float rstd = rsqrtf(red[0] / (float)KM + LN_EPS);
        __syncthreads();

        if (tid < KM) t_s[tid] = tanhf(d * rstd * kg[tid] + kbe[tid]);
        __syncthreads();

        float acc = kb2[tid];
        #pragma unroll 4
        for (int k = 0; k < KM; ++k) acc = fmaf(t_s[k], kW2[k * HID + tid], acc);
        keys[j * HID + tid] = acc;
        return;
    }

    // ---------------- sizepred: 32 batches, H = Z @ sW1 then LN/ReLU/dot ----------------
    float (*z_s)[ZPAD] = (float(*)[ZPAD])smem;   // [256][36], z_s[k][b]
    const int b0 = blk * SP_BATCH;

    {
        const float4* z4 = (const float4*)z;
        #pragma unroll
        for (int i = 0; i < 8; ++i) {
            const int idx = tid + 256 * i;
            const int r = idx >> 6, c4 = idx & 63;
            const float4 v = z4[(size_t)(b0 + r) * 64 + c4];
            z_s[4 * c4 + 0][r] = v.x;
            z_s[4 * c4 + 1][r] = v.y;
            z_s[4 * c4 + 2][r] = v.z;
            z_s[4 * c4 + 3][r] = v.w;
        }
    }
    __syncthreads();

    const int cq = tid & 31;   // col quad: cols 4cq..4cq+3
    const int bg = tid >> 5;   // batch group: batches 4bg..4bg+3

    float acc[4][4];
    #pragma unroll
    for (int bi = 0; bi < 4; ++bi)
        #pragma unroll
        for (int ci = 0; ci < 4; ++ci) acc[bi][ci] = 0.f;

    const float4* w4p = (const float4*)sW1;
    #pragma unroll 4
    for (int k = 0; k < HID; ++k) {
        const float4 wv = w4p[k * 32 + cq];
        const float4 zb = *(const float4*)&z_s[k][bg * 4];
        const float zz[4] = {zb.x, zb.y, zb.z, zb.w};
        const float ww[4] = {wv.x, wv.y, wv.z, wv.w};
        #pragma unroll
        for (int bi = 0; bi < 4; ++bi)
            #pragma unroll
            for (int ci = 0; ci < 4; ++ci)
                acc[bi][ci] = fmaf(zz[bi], ww[ci], acc[bi][ci]);
    }

    const float4 g4v  = ((const float4*)sg)[cq];
    const float4 be4v = ((const float4*)sbe)[cq];
    const float4 w24v = ((const float4*)sW2)[cq];
    const float g4[4]  = {g4v.x, g4v.y, g4v.z, g4v.w};
    const float be4[4] = {be4v.x, be4v.y, be4v.z, be4v.w};
    const float w24[4] = {w24v.x, w24v.y, w24v.z, w24v.w};
    const float sb2v = sb2[0];
    const float b1_0 = sb1[4 * cq + 0], b1_1 = sb1[4 * cq + 1],
                b1_2 = sb1[4 * cq + 2], b1_3 = sb1[4 * cq + 3];

    #pragma unroll
    for (int bi = 0; bi < 4; ++bi) {
        float a[4] = {acc[bi][0] + b1_0, acc[bi][1] + b1_1,
                      acc[bi][2] + b1_2, acc[bi][3] + b1_3};
        float s = a[0] + a[1] + a[2] + a[3];
        #pragma unroll
        for (int off = 1; off < 32; off <<= 1) s += __shfl_xor(s, off, 64);
        const float mu = s * (1.f / (float)SM);
        float d[4], vs = 0.f;
        #pragma unroll
        for (int ci = 0; ci < 4; ++ci) { d[ci] = a[ci] - mu; vs = fmaf(d[ci], d[ci], vs); }
        #pragma unroll
        for (int off = 1; off < 32; off <<= 1) vs += __shfl_xor(vs, off, 64);
        const float rstd = rsqrtf(vs * (1.f / (float)SM) + LN_EPS);

        float p = 0.f;
        #pragma unroll
        for (int ci = 0; ci < 4; ++ci) {
            float h = fmaf(d[ci] * rstd, g4[ci], be4[ci]);
            h = fmaxf(h, 0.f);
            p = fmaf(h, w24[ci], p);
        }
        #pragma unroll
        for (int off = 1; off < 32; off <<= 1) p += __shfl_xor(p, off, 64);

        if (cq == 0) {
            const int b = b0 + bg * 4 + bi;
            const float logit = p + sb2v;
            int n = (int)rintf(logit);       // round-half-even == jnp.round
            n = min(max(n, 0), MAXN - 1);
            out_logits[b] = logit;
            out_nf[b] = (float)n;
            n_ws[b] = n;
        }
    }
}

// ---------------- Kernel 2: mega — fill(j>=n) + decode(j<n), 4 batches/block ----------------
__global__ void __launch_bounds__(256) mega_kernel(
    const float* __restrict__ z, const float* __restrict__ keys,
    const int* __restrict__ n_ws,
    const float* __restrict__ dW1, const float* __restrict__ db1,
    const float* __restrict__ dW2, const float* __restrict__ db2,
    float* __restrict__ out0)
{
    __shared__ __align__(16) float z_s[4][HID];        // 4 KB
    __shared__ __align__(16) float s_s[HID][4];        // 4 KB
    __shared__ __align__(16) float t_s[DM][4];         // 3 KB
    __shared__ __align__(16) float pbuf[4 * DM * 4];   // 12 KB: hp, reused as op
    __shared__ int n_s[4];
    __shared__ int rlist[4 * (MAXN - 1)];              // ~1 KB

    const int blk = blockIdx.x;
    const int tid = threadIdx.x;
    const int w = tid >> 6, lane = tid & 63;
    const int b0 = blk * 4;

    if (tid < 4) n_s[tid] = n_ws[b0 + tid];
    __syncthreads();

    // ---- fill invalid rows j >= n (disjoint from decoded rows) ----
    const float4 zf = make_float4(0.f, 0.f, 0.f, 0.f);
    #pragma unroll
    for (int bi = 0; bi < 4; ++bi) {
        const int n = n_s[bi];
        float4* o4 = (float4*)(out0 + (size_t)(b0 + bi) * (MAXN * DIM)) + n * 32;
        const int cnt4 = (MAXN - n) * 32;
        for (int idx = tid; idx < cnt4; idx += 256) o4[idx] = zf;
    }

    const int total = n_s[0] + n_s[1] + n_s[2] + n_s[3];
    if (total == 0) return;

    // ---- stage z rows + build block-local row list ----
    {
        const int r = tid >> 6, c4 = tid & 63;
        ((float4*)z_s[r])[c4] = ((const float4*)(z + (size_t)(b0 + r) * HID))[c4];
    }
    if (tid < 4) {
        int off = 0;
        for (int i = 0; i < tid; ++i) off += n_s[i];
        for (int j = 0; j < n_s[tid]; ++j) rlist[off + j] = (tid << 6) | j;
    }
    __syncthreads();

    float (*hp)[DM][4]  = (float(*)[DM][4])pbuf;    // GEMV1 partials
    float (*op)[DIM][4] = (float(*)[DIM][4])pbuf;   // GEMV2 partials (aliased)

    // ---- decode valid rows, 4 per iteration (verified tile) ----
    for (int base = 0; base < total; base += 4) {
        const int rcnt = min(4, total - base);
        int bs[4], js[4];
        #pragma unroll
        for (int r = 0; r < 4; ++r) {
            const int e = rlist[base + min(r, rcnt - 1)];
            bs[r] = e >> 6; js[r] = e & 63;
        }

        // stage s[k][r] = z[b_r][k] * keys[j_r][k]   (k == tid; z from LDS)
        #pragma unroll
        for (int r = 0; r < 4; ++r)
            s_s[tid][r] = z_s[bs[r]][tid] * keys[js[r] * HID + tid];
        __syncthreads();

        // GEMV1: wave w covers k in [64w, 64w+64); lane<48 owns cols 4lane..4lane+3
        if (lane < 48) {
            float a[4][4];
            #pragma unroll
            for (int r = 0; r < 4; ++r)
                #pragma unroll
                for (int c = 0; c < 4; ++c) a[r][c] = 0.f;
            const int k0 = w * 64;
            #pragma unroll 8
            for (int kk = 0; kk < 64; ++kk) {
                const int k = k0 + kk;
                const float4 wv = ((const float4*)dW1)[(size_t)k * 48 + lane];
                const float4 sv = *(const float4*)&s_s[k][0];
                const float sr[4] = {sv.x, sv.y, sv.z, sv.w};
                const float wc[4] = {wv.x, wv.y, wv.z, wv.w};
                #pragma unroll
                for (int r = 0; r < 4; ++r)
                    #pragma unroll
                    for (int c = 0; c < 4; ++c)
                        a[r][c] = fmaf(sr[r], wc[c], a[r][c]);
            }
            #pragma unroll
            for (int c = 0; c < 4; ++c)
                *(float4*)&hp[w][4 * lane + c][0] =
                    make_float4(a[0][c], a[1][c], a[2][c], a[3][c]);
        }
        __syncthreads();

        if (tid < DM) {
            const float4 p0 = *(const float4*)&hp[0][tid][0];
            const float4 p1 = *(const float4*)&hp[1][tid][0];
            const float4 p2 = *(const float4*)&hp[2][tid][0];
            const float4 p3 = *(const float4*)&hp[3][tid][0];
            const float bb = db1[tid];
            *(float4*)&t_s[tid][0] = make_float4(
                tanhf(p0.x + p1.x + p2.x + p3.x + bb),
                tanhf(p0.y + p1.y + p2.y + p3.y + bb),
                tanhf(p0.z + p1.z + p2.z + p3.z + bb),
                tanhf(p0.w + p1.w + p2.w + p3.w + bb));
        }
        __syncthreads();   // hp reads done; safe to alias as op

        // GEMV2: wave w covers k in [48w, 48w+48); lane<32 owns cols 4lane..4lane+3
        if (lane < 32) {
            float o[4][4];
            #pragma unroll
            for (int r = 0; r < 4; ++r)
                #pragma unroll
                for (int c = 0; c < 4; ++c) o[r][c] = 0.f;
            const int k1 = w * 48;
            #pragma unroll 8
            for (int kk = 0; kk < 48; ++kk) {
                const int k = k1 + kk;
                const float4 wv = ((const float4*)dW2)[(size_t)k * 32 + lane];
                const float4 tv = *(const float4*)&t_s[k][0];
                const float tr[4] = {tv.x, tv.y, tv.z, tv.w};
                const float wc[4] = {wv.x, wv.y, wv.z, wv.w};
                #pragma unroll
                for (int r = 0; r < 4; ++r)
                    #pragma unroll
                    for (int c = 0; c < 4; ++c)
                        o[r][c] = fmaf(tr[r], wc[c], o[r][c]);
            }
            #pragma unroll
            for (int c = 0; c < 4; ++c)
                *(float4*)&op[w][4 * lane + c][0] =
                    make_float4(o[0][c], o[1][c], o[2][c], o[3][c]);
        }
        __syncthreads();

        if (tid < DIM) {
            const float4 q0 = *(const float4*)&op[0][tid][0];
            const float4 q1 = *(const float4*)&op[1][tid][0];
            const float4 q2 = *(const float4*)&op[2][tid][0];
            const float4 q3 = *(const float4*)&op[3][tid][0];
            const float bb = db2[tid];
            const float ov[4] = {q0.x + q1.x + q2.x + q3.x + bb,
                                 q0.y + q1.y + q2.y + q3.y + bb,
                                 q0.z + q1.z + q2.z + q3.z + bb,
                                 q0.w + q1.w + q2.w + q3.w + bb};
            #pragma unroll
            for (int r = 0; r < 4; ++r)
                if (r < rcnt)
                    out0[((size_t)(b0 + bs[r]) * MAXN + js[r]) * DIM + tid] = ov[r];
        }
        __syncthreads();   // protect s_s/t_s/op before next group
    }
}

extern "C" void kernel_launch(void* const* d_in, const int* in_sizes, int n_in,
                              void* d_out, int out_size, void* d_ws, size_t ws_size,
                              hipStream_t stream)
{
    const float* z   = (const float*)d_in[0];
    const float* kW1 = (const float*)d_in[1];
    const float* kb1 = (const float*)d_in[2];
    const float* kg  = (const float*)d_in[3];
    const float* kbe = (const float*)d_in[4];
    const float* kW2 = (const float*)d_in[5];
    const float* kb2 = (const float*)d_in[6];
    const float* dW1 = (const float*)d_in[7];
    const float* db1 = (const float*)d_in[8];
    const float* dW2 = (const float*)d_in[9];
    const float* db2 = (const float*)d_in[10];
    const float* sW1 = (const float*)d_in[11];
    const float* sb1 = (const float*)d_in[12];
    const float* sg  = (const float*)d_in[13];
    const float* sbe = (const float*)d_in[14];
    const float* sW2 = (const float*)d_in[15];
    const float* sb2 = (const float*)d_in[16];

    float* out0       = (float*)d_out;                         // [B, 64, 128]
    float* out_logits = out0 + (size_t)B_SZ * MAXN * DIM;      // [B, 1]
    float* out_nf     = out_logits + B_SZ;                     // [B]

    float* keys = (float*)d_ws;                                // 64 KB
    int*   n_ws = (int*)((char*)d_ws + 65536);                 // 32 KB

    sp_keys_kernel<<<SP_BLOCKS + MAXN, 256, 0, stream>>>(
        z, kW1, kb1, kg, kbe, kW2, kb2,
        sW1, sb1, sg, sbe, sW2, sb2,
        out_logits, out_nf, n_ws, keys);

    mega_kernel<<<B_SZ / 4, 256, 0, stream>>>(
        z, keys, n_ws, dW1, db1, dW2, db2, out0);
}